// Round 19
// baseline (743.691 us; speedup 1.0000x reference)
//
#include <hip/hip_runtime.h>
#include <hip/hip_bf16.h>

#define HD 1024   // hidden
#define ID 4096   // intermediate
#define NE 8      // experts
#define NT 4096   // tokens (2*2048)
#define NSLOT (NT*2)

typedef __attribute__((ext_vector_type(4))) float f32x4;
typedef __attribute__((ext_vector_type(8))) short bf16x8;
typedef __attribute__((ext_vector_type(4))) unsigned int u32x4;
typedef __attribute__((ext_vector_type(2))) unsigned int u32x2;
typedef unsigned short u16;

__device__ __forceinline__ u16 f2b(float f) {
  __hip_bfloat16 h = __float2bfloat16(f);
  return __builtin_bit_cast(unsigned short, h);
}
__device__ __forceinline__ unsigned int pack2(float a, float b) {
  return (unsigned int)f2b(a) | ((unsigned int)f2b(b) << 16);
}
__device__ __forceinline__ void gload16(const void* g, void* l) {
  __builtin_amdgcn_global_load_lds(
      (const __attribute__((address_space(1))) unsigned int*)g,
      (__attribute__((address_space(3))) unsigned int*)l, 16, 0, 0);
}
// fast gelu-tanh: tanh(u) = 1 - 2/(exp(2u)+1)
__device__ __forceinline__ float gelu_tanh(float v) {
  float c = v + 0.044715f * v * v * v;
  float u = 1.5957691216057308f * c;
  float t = 1.0f - 2.0f / (__expf(u) + 1.0f);
  return 0.5f * v * (1.0f + t);
}

// ---- merged W1/W2 transpose+convert: [E][R][C] f32 -> [E][C][R] bf16 ----
__global__ __launch_bounds__(256) void k_transpose2(
    const float* __restrict__ W1, u16* __restrict__ w1t,
    const float* __restrict__ W2, u16* __restrict__ w2t) {
  __shared__ float tile[64][65];
  int id = blockIdx.x;                 // [0, 16384)
  const float* src;
  u16* dst;
  int R, C, e, rem;
  if (id < 8192) {                     // W1: R=HD, C=ID
    e = id >> 10; rem = id & 1023;
    src = W1; dst = w1t; R = HD; C = ID;
  } else {                             // W2: R=ID, C=HD
    id -= 8192;
    e = id >> 10; rem = id & 1023;
    src = W2; dst = w2t; R = ID; C = HD;
  }
  int ctiles = C >> 6;
  int c0 = (rem % ctiles) * 64;
  int r0 = (rem / ctiles) * 64;
  int t = threadIdx.x;
  const float* s = src + (size_t)e * R * C;
#pragma unroll
  for (int i = 0; i < 16; ++i) {
    int r = i * 4 + (t >> 6);
    tile[r][t & 63] = s[(size_t)(r0 + r) * C + c0 + (t & 63)];
  }
  __syncthreads();
  u16* d = dst + (size_t)e * R * C;
#pragma unroll
  for (int i = 0; i < 4; ++i) {
    int c = i * 16 + (t >> 4);
    int rb = (t & 15) * 4;
    u32x2 p;
    p[0] = pack2(tile[rb + 0][c], tile[rb + 1][c]);
    p[1] = pack2(tile[rb + 2][c], tile[rb + 3][c]);
    *(u32x2*)&d[(size_t)(c0 + c) * R + r0 + rb] = p;
  }
}

// ------- router: logits, softmax, top-2, lists; also x->bf16 and psum -------
__global__ __launch_bounds__(256) void k_router(
    const float* __restrict__ x, const float* __restrict__ Wr,
    const float* __restrict__ br, int* __restrict__ cnt,
    int* __restrict__ slotE, int* __restrict__ slotLoc,
    float* __restrict__ slotW, float* __restrict__ psumG,
    u16* __restrict__ xb) {
  __shared__ float wrt[NE * HD];          // WrT [e][h]
  __shared__ float blkp[NE];
  int t = threadIdx.x;
  if (t < NE) blkp[t] = 0.0f;
  for (int i = t; i < NE * HD; i += 256) wrt[(i & 7) * HD + (i >> 3)] = Wr[i];
  __syncthreads();
  int wave = t >> 6, lane = t & 63;
  int token = blockIdx.x * 4 + wave;
  const float* xr = x + (size_t)token * HD;
  u16* xbr = xb + (size_t)token * HD;
  float acc[NE] = {0, 0, 0, 0, 0, 0, 0, 0};
#pragma unroll 4
  for (int j = 0; j < 16; ++j) {
    int h = j * 64 + lane;
    float xv = xr[h];
    xbr[h] = f2b(xv);                    // fused x -> bf16
#pragma unroll
    for (int e = 0; e < NE; ++e) acc[e] += xv * wrt[e * HD + h];
  }
#pragma unroll
  for (int d = 1; d < 64; d <<= 1) {
#pragma unroll
    for (int e = 0; e < NE; ++e) acc[e] += __shfl_xor(acc[e], d, 64);
  }
  if (lane == 0) {
    float lg[NE], p[NE];
    float m = -1e30f;
#pragma unroll
    for (int e = 0; e < NE; ++e) { lg[e] = acc[e] + br[e]; m = fmaxf(m, lg[e]); }
    float s = 0.f;
#pragma unroll
    for (int e = 0; e < NE; ++e) { p[e] = expf(lg[e] - m); s += p[e]; }
    float inv = 1.0f / s;
    int i1 = 0, i2 = -1;
    float v1 = -1.f, v2 = -1.f;
#pragma unroll
    for (int e = 0; e < NE; ++e) {
      p[e] *= inv;
      atomicAdd(&blkp[e], p[e]);
      if (p[e] > v1) { v2 = v1; i2 = i1; v1 = p[e]; i1 = e; }
      else if (p[e] > v2) { v2 = p[e]; i2 = e; }
    }
    float wsum = v1 + v2;
    int l1 = atomicAdd(&cnt[i1], 1);
    int l2 = atomicAdd(&cnt[i2], 1);
    slotE[token * 2] = i1;     slotLoc[token * 2] = l1;     slotW[token * 2] = v1 / wsum;
    slotE[token * 2 + 1] = i2; slotLoc[token * 2 + 1] = l2; slotW[token * 2 + 1] = v2 / wsum;
  }
  __syncthreads();
  if (t < NE) atomicAdd(&psumG[t], blkp[t]);
}

// ---------------- finalize: offsets + aux loss (trivial) ----------------
__global__ void k_finalize(const float* __restrict__ psumG, const int* __restrict__ cnt,
                           int* __restrict__ off, float* __restrict__ out_aux) {
  if (threadIdx.x == 0) {
    int o = 0;
    float a = 0.f;
    for (int e = 0; e < NE; ++e) {
      off[e] = o;
      o += cnt[e];
      a += ((float)cnt[e] / (float)NSLOT) * (psumG[e] / (float)NT);
    }
    off[NE] = o;
    out_aux[0] = (float)NE * a * 0.01f;
  }
}

// ---------------- scatter: build per-expert row lists ----------------
__global__ void k_scatter(const int* __restrict__ slotE, const int* __restrict__ slotLoc,
                          const float* __restrict__ slotW, const int* __restrict__ off,
                          int* __restrict__ rowTok, float* __restrict__ rowW) {
  int i = blockIdx.x * 256 + threadIdx.x;  // < NSLOT
  int pos = off[slotE[i]] + slotLoc[i];
  if (pos < 0) pos = 0;
  if (pos >= NSLOT) pos = NSLOT - 1;
  rowTok[pos] = i >> 1;
  rowW[pos] = slotW[i];
}

// Stage one 128x32 A-tile (8 KB) into buffer `bf`: 2 gload16/thread.
#define STGA(bf) do { \
    gload16(srcA0, &As[bf][c0 * 8]); \
    gload16(srcA1, &As[bf][c1 * 8]); \
    srcA0 += 32; srcA1 += 32; \
  } while (0)

// Load 4 B-fragments for K-step `ktv` directly to registers (16B each, L2-hot).
#define LOADB(dst, ktv) do { \
    size_t kb_ = (size_t)(ktv) * 32 + kfrag; \
    dst[0] = *(const bf16x8*)(bbl0 + kb_); \
    dst[1] = *(const bf16x8*)(bbl1 + kb_); \
    dst[2] = *(const bf16x8*)(bbl2 + kb_); \
    dst[3] = *(const bf16x8*)(bbl3 + kb_); \
  } while (0)

// One K-step: wait own A-tile, barrier, ds_read A-frags, prefetch next B,
// MFMA with current B, restage A two tiles ahead.
#define KSTEP(kt, cur, nxt, NKV) do { \
    if ((kt) + 1 < (NKV)) asm volatile("s_waitcnt vmcnt(6)" ::: "memory"); \
    else                  asm volatile("s_waitcnt vmcnt(0)" ::: "memory"); \
    __builtin_amdgcn_s_barrier(); \
    const u16* ap = &As[rb][aoff]; \
    bf16x8 af[4]; \
    _Pragma("unroll") for (int m = 0; m < 4; ++m) \
      af[m] = *(const bf16x8*)(ap + m * 16 * 32); \
    int ktn = ((kt) + 1 < (NKV)) ? (kt) + 1 : (NKV) - 1; \
    LOADB(nxt, ktn); \
    _Pragma("unroll") for (int m = 0; m < 4; ++m) \
      _Pragma("unroll") for (int n = 0; n < 4; ++n) \
        acc[m][n] = __builtin_amdgcn_mfma_f32_16x16x32_bf16(af[m], cur[n], acc[m][n], 0, 0, 0); \
    if ((kt) + 2 < (NKV)) { \
      int sb = rb + 2; if (sb >= 3) sb -= 3; \
      STGA(sb); \
    } \
    rb = (rb == 2) ? 0 : rb + 1; \
  } while (0)

// ---------------- GEMM1: h = gelu(xb[gather] @ W1[e] + b1[e]) ----------------
// 128x128 tile, BK=32, 4 waves, A: 3-buffer LDS depth-2; B: streamed to
// registers (double-buffered 1 step ahead, L2-hot via m-inner ordering).
__global__ __launch_bounds__(256, 4) void k_gemm1(
    const u16* __restrict__ xb, const u16* __restrict__ w1t,
    const float* __restrict__ b1, u16* __restrict__ hbuf,
    const int* __restrict__ cnt, const int* __restrict__ off,
    const int* __restrict__ rowTok) {
  const int NWG = NE * 32 * 32;
  int bid = blockIdx.x;
  int wg = (bid & 7) * (NWG / 8) + (bid >> 3);
  int e = wg >> 10;
  int rem = wg & 1023;
  int n0 = (rem >> 5) * 128;          // n outer
  int m0 = (rem & 31) * 128;          // m inner (B-panel peers consecutive)
  int ce = cnt[e];
  if (m0 >= ce) return;
  int oe = off[e];
  __shared__ u16 As[3][128 * 32];
  __shared__ int rtok[128];
  int t = threadIdx.x;
  if (t < 128) {
    int r = m0 + t;
    if (r >= ce) r = ce - 1;
    int tok = rowTok[oe + r];
    rtok[t] = (tok < 0) ? 0 : (tok >= NT ? NT - 1 : tok);
  }
  __syncthreads();
  // A chunk swizzle: LDS chunk c holds global 16B-chunk j=(c&3)^((c>>3)&3)
  int c0 = t, c1 = t + 256;
  int js0 = (c0 & 3) ^ ((c0 >> 3) & 3);
  int js1 = (c1 & 3) ^ ((c1 >> 3) & 3);
  const u16* srcA0 = xb + (size_t)rtok[c0 >> 2] * HD + js0 * 8;
  const u16* srcA1 = xb + (size_t)rtok[c1 >> 2] * HD + js1 * 8;
  int wave = t >> 6, lane = t & 63;
  int wr = wave >> 1, wc = wave & 1;
  int arow = wr * 64 + (lane & 15);
  int aoff = arow * 32 + ((lane >> 4) ^ ((arow >> 1) & 3)) * 8;   // swizzled read
  // B fragment base pointers: w1t[e][col][k], 16B contiguous per fragment
  size_t kfrag = (size_t)(lane >> 4) * 8;
  const u16* bbase = w1t + (size_t)e * ID * HD;
  const u16* bbl0 = bbase + (size_t)(n0 + wc * 64 + 0 * 16 + (lane & 15)) * HD;
  const u16* bbl1 = bbase + (size_t)(n0 + wc * 64 + 1 * 16 + (lane & 15)) * HD;
  const u16* bbl2 = bbase + (size_t)(n0 + wc * 64 + 2 * 16 + (lane & 15)) * HD;
  const u16* bbl3 = bbase + (size_t)(n0 + wc * 64 + 3 * 16 + (lane & 15)) * HD;
  f32x4 acc[4][4] = {};
  const int NK = HD / 32;             // 32 (even)
  bf16x8 bvA[4], bvB[4];
  STGA(0);
  STGA(1);
  LOADB(bvA, 0);
  int rb = 0;
  for (int k2 = 0; k2 < NK; k2 += 2) {
    KSTEP(k2,     bvA, bvB, NK);
    KSTEP(k2 + 1, bvB, bvA, NK);
  }
  const float* b1e = b1 + (size_t)e * ID + n0;
#pragma unroll
  for (int n = 0; n < 4; ++n) {
    int col = wc * 64 + n * 16 + (lane & 15);
    float bias = b1e[col];
#pragma unroll
    for (int m = 0; m < 4; ++m) {
      int rbase = wr * 64 + m * 16 + (lane >> 4) * 4;
#pragma unroll
      for (int r = 0; r < 4; ++r) {
        int grow = m0 + rbase + r;
        if (grow < ce) {
          float v = acc[m][n][r] + bias;
          hbuf[(size_t)(oe + grow) * ID + n0 + col] = f2b(gelu_tanh(v));
        }
      }
    }
  }
}

// ------- GEMM2 (split-K=2, fused combine): out[tok] += (h@W2 + b2) * w -------
__global__ __launch_bounds__(256, 4) void k_gemm2(
    const u16* __restrict__ hbuf, const u16* __restrict__ w2t,
    const float* __restrict__ b2, float* __restrict__ out,
    const int* __restrict__ cnt, const int* __restrict__ off,
    const int* __restrict__ rowTok, const float* __restrict__ rowW) {
  const int NWG = NE * 32 * 2 * 8;
  int bid = blockIdx.x;
  int wg = (bid & 7) * (NWG / 8) + (bid >> 3);
  int e = wg >> 9;
  int rem = wg & 511;
  int ks = rem >> 8;                  // outer
  int n0 = ((rem >> 5) & 7) * 128;    // middle
  int m0 = (rem & 31) * 128;          // inner
  int ce = cnt[e];
  if (m0 >= ce) return;
  int oe = off[e];
  int k0 = ks * (ID / 2);
  __shared__ u16 As[3][128 * 32];
  __shared__ int rtok[128];
  __shared__ float rw[128];
  int t = threadIdx.x;
  if (t < 128) {
    int r = m0 + t;
    int rc = (r < ce) ? r : ce - 1;
    int tok = rowTok[oe + rc];
    rtok[t] = (tok < 0) ? 0 : (tok >= NT ? NT - 1 : tok);
    rw[t] = (r < ce) ? rowW[oe + r] : 0.0f;
  }
  __syncthreads();
  int c0 = t, c1 = t + 256;
  int js0 = (c0 & 3) ^ ((c0 >> 3) & 3);
  int js1 = (c1 & 3) ^ ((c1 >> 3) & 3);
  int rA0 = m0 + (c0 >> 2); if (rA0 >= ce) rA0 = ce - 1;
  int rA1 = m0 + (c1 >> 2); if (rA1 >= ce) rA1 = ce - 1;
  const u16* srcA0 = hbuf + (size_t)(oe + rA0) * ID + k0 + js0 * 8;
  const u16* srcA1 = hbuf + (size_t)(oe + rA1) * ID + k0 + js1 * 8;
  int wave = t >> 6, lane = t & 63;
  int wr = wave >> 1, wc = wave & 1;
  int arow = wr * 64 + (lane & 15);
  int aoff = arow * 32 + ((lane >> 4) ^ ((arow >> 1) & 3)) * 8;
  size_t kfrag = (size_t)(lane >> 4) * 8;
  const u16* bbase = w2t + (size_t)e * HD * ID + k0;
  const u16* bbl0 = bbase + (size_t)(n0 + wc * 64 + 0 * 16 + (lane & 15)) * ID;
  const u16* bbl1 = bbase + (size_t)(n0 + wc * 64 + 1 * 16 + (lane & 15)) * ID;
  const u16* bbl2 = bbase + (size_t)(n0 + wc * 64 + 2 * 16 + (lane & 15)) * ID;
  const u16* bbl3 = bbase + (size_t)(n0 + wc * 64 + 3 * 16 + (lane & 15)) * ID;
  f32x4 acc[4][4] = {};
  const int NK = (ID / 2) / 32;       // 64 (even)
  bf16x8 bvA[4], bvB[4];
  STGA(0);
  STGA(1);
  LOADB(bvA, 0);
  int rb = 0;
  for (int k2 = 0; k2 < NK; k2 += 2) {
    KSTEP(k2,     bvA, bvB, NK);
    KSTEP(k2 + 1, bvB, bvA, NK);
  }
  const float* b2e = b2 + (size_t)e * HD + n0;
#pragma unroll
  for (int n = 0; n < 4; ++n) {
    int col = wc * 64 + n * 16 + (lane & 15);
    float bias = (ks == 0) ? b2e[col] : 0.0f;
#pragma unroll
    for (int m = 0; m < 4; ++m) {
      int rbase = wr * 64 + m * 16 + (lane >> 4) * 4;
#pragma unroll
      for (int r = 0; r < 4; ++r) {
        int grow = m0 + rbase + r;
        if (grow < ce) {
          float v = (acc[m][n][r] + bias) * rw[rbase + r];
          atomicAdd(&out[(size_t)rtok[rbase + r] * HD + n0 + col], v);
        }
      }
    }
  }
}

extern "C" void kernel_launch(void* const* d_in, const int* in_sizes, int n_in,
                              void* d_out, int out_size, void* d_ws, size_t ws_size,
                              hipStream_t stream) {
  const float* x  = (const float*)d_in[0];
  const float* Wr = (const float*)d_in[1];
  const float* br = (const float*)d_in[2];
  const float* W1 = (const float*)d_in[3];
  const float* b1 = (const float*)d_in[4];
  const float* W2 = (const float*)d_in[5];
  const float* b2 = (const float*)d_in[6];
  float* out = (float*)d_out;

  char* ws = (char*)d_ws;
  size_t o = 0;
  auto alloc = [&](size_t bytes) {
    void* p = ws + o;
    o = (o + bytes + 255) & ~(size_t)255;
    return p;
  };
  u16* xb    = (u16*)alloc((size_t)NT * HD * 2);
  u16* w1t   = (u16*)alloc((size_t)NE * ID * HD * 2);
  u16* w2t   = (u16*)alloc((size_t)NE * ID * HD * 2);
  u16* hbuf  = (u16*)alloc((size_t)NSLOT * ID * 2);
  int* cnt     = (int*)alloc(NE * 4);
  float* psumG = (float*)alloc(NE * 4);
  int* off     = (int*)alloc(16 * 4);
  int* slotE   = (int*)alloc(NSLOT * 4);
  int* slotLoc = (int*)alloc(NSLOT * 4);
  float* slotW = (float*)alloc(NSLOT * 4);
  int* rowTok  = (int*)alloc(NSLOT * 4);
  float* rowW  = (float*)alloc(NSLOT * 4);

  if (ws_size < o) return;  // workspace too small: fail cleanly, not a fault

  (void)hipMemsetAsync(cnt, 0, NE * 4, stream);
  (void)hipMemsetAsync(psumG, 0, NE * 4, stream);
  (void)hipMemsetAsync(out, 0, (size_t)out_size * 4, stream);
  k_transpose2<<<16384, 256, 0, stream>>>(W1, w1t, W2, w2t);
  k_router<<<NT / 4, 256, 0, stream>>>(x, Wr, br, cnt, slotE, slotLoc, slotW, psumG, xb);
  k_finalize<<<1, 64, 0, stream>>>(psumG, cnt, off, out + (size_t)NT * HD);
  k_scatter<<<NSLOT / 256, 256, 0, stream>>>(slotE, slotLoc, slotW, off, rowTok, rowW);
  k_gemm1<<<NE * 32 * 32, 256, 0, stream>>>(xb, w1t, b1, hbuf, cnt, off, rowTok);
  k_gemm2<<<NE * 32 * 2 * 8, 256, 0, stream>>>(hbuf, w2t, b2, out, cnt, off, rowTok, rowW);
}

// Round 20
// 470.897 us; speedup vs baseline: 1.5793x; 1.5793x over previous
//
#include <hip/hip_runtime.h>
#include <hip/hip_bf16.h>

#define HD 1024   // hidden
#define ID 4096   // intermediate
#define NE 8      // experts
#define NT 4096   // tokens (2*2048)
#define NSLOT (NT*2)

typedef __attribute__((ext_vector_type(4))) float f32x4;
typedef __attribute__((ext_vector_type(8))) short bf16x8;
typedef __attribute__((ext_vector_type(4))) unsigned int u32x4;
typedef __attribute__((ext_vector_type(2))) unsigned int u32x2;
typedef unsigned short u16;

__device__ __forceinline__ u16 f2b(float f) {
  __hip_bfloat16 h = __float2bfloat16(f);
  return __builtin_bit_cast(unsigned short, h);
}
__device__ __forceinline__ unsigned int pack2(float a, float b) {
  return (unsigned int)f2b(a) | ((unsigned int)f2b(b) << 16);
}
__device__ __forceinline__ void gload16(const void* g, void* l) {
  __builtin_amdgcn_global_load_lds(
      (const __attribute__((address_space(1))) unsigned int*)g,
      (__attribute__((address_space(3))) unsigned int*)l, 16, 0, 0);
}
// fast gelu-tanh: tanh(u) = 1 - 2/(exp(2u)+1)
__device__ __forceinline__ float gelu_tanh(float v) {
  float c = v + 0.044715f * v * v * v;
  float u = 1.5957691216057308f * c;
  float t = 1.0f - 2.0f / (__expf(u) + 1.0f);
  return 0.5f * v * (1.0f + t);
}

// ---- merged W1/W2 transpose+convert: [E][R][C] f32 -> [E][C][R] bf16 ----
__global__ __launch_bounds__(256) void k_transpose2(
    const float* __restrict__ W1, u16* __restrict__ w1t,
    const float* __restrict__ W2, u16* __restrict__ w2t) {
  __shared__ float tile[64][65];
  int id = blockIdx.x;                 // [0, 16384)
  const float* src;
  u16* dst;
  int R, C, e, rem;
  if (id < 8192) {                     // W1: R=HD, C=ID
    e = id >> 10; rem = id & 1023;
    src = W1; dst = w1t; R = HD; C = ID;
  } else {                             // W2: R=ID, C=HD
    id -= 8192;
    e = id >> 10; rem = id & 1023;
    src = W2; dst = w2t; R = ID; C = HD;
  }
  int ctiles = C >> 6;
  int c0 = (rem % ctiles) * 64;
  int r0 = (rem / ctiles) * 64;
  int t = threadIdx.x;
  const float* s = src + (size_t)e * R * C;
#pragma unroll
  for (int i = 0; i < 16; ++i) {
    int r = i * 4 + (t >> 6);
    tile[r][t & 63] = s[(size_t)(r0 + r) * C + c0 + (t & 63)];
  }
  __syncthreads();
  u16* d = dst + (size_t)e * R * C;
#pragma unroll
  for (int i = 0; i < 4; ++i) {
    int c = i * 16 + (t >> 4);
    int rb = (t & 15) * 4;
    u32x2 p;
    p[0] = pack2(tile[rb + 0][c], tile[rb + 1][c]);
    p[1] = pack2(tile[rb + 2][c], tile[rb + 3][c]);
    *(u32x2*)&d[(size_t)(c0 + c) * R + r0 + rb] = p;
  }
}

// ------- router: logits, softmax, top-2, lists; also x->bf16 and psum -------
__global__ __launch_bounds__(256) void k_router(
    const float* __restrict__ x, const float* __restrict__ Wr,
    const float* __restrict__ br, int* __restrict__ cnt,
    int* __restrict__ slotE, int* __restrict__ slotLoc,
    float* __restrict__ slotW, float* __restrict__ psumG,
    u16* __restrict__ xb) {
  __shared__ float wrt[NE * HD];          // WrT [e][h]
  __shared__ float blkp[NE];
  int t = threadIdx.x;
  if (t < NE) blkp[t] = 0.0f;
  for (int i = t; i < NE * HD; i += 256) wrt[(i & 7) * HD + (i >> 3)] = Wr[i];
  __syncthreads();
  int wave = t >> 6, lane = t & 63;
  int token = blockIdx.x * 4 + wave;
  const float* xr = x + (size_t)token * HD;
  u16* xbr = xb + (size_t)token * HD;
  float acc[NE] = {0, 0, 0, 0, 0, 0, 0, 0};
#pragma unroll 4
  for (int j = 0; j < 16; ++j) {
    int h = j * 64 + lane;
    float xv = xr[h];
    xbr[h] = f2b(xv);                    // fused x -> bf16
#pragma unroll
    for (int e = 0; e < NE; ++e) acc[e] += xv * wrt[e * HD + h];
  }
#pragma unroll
  for (int d = 1; d < 64; d <<= 1) {
#pragma unroll
    for (int e = 0; e < NE; ++e) acc[e] += __shfl_xor(acc[e], d, 64);
  }
  if (lane == 0) {
    float lg[NE], p[NE];
    float m = -1e30f;
#pragma unroll
    for (int e = 0; e < NE; ++e) { lg[e] = acc[e] + br[e]; m = fmaxf(m, lg[e]); }
    float s = 0.f;
#pragma unroll
    for (int e = 0; e < NE; ++e) { p[e] = expf(lg[e] - m); s += p[e]; }
    float inv = 1.0f / s;
    int i1 = 0, i2 = -1;
    float v1 = -1.f, v2 = -1.f;
#pragma unroll
    for (int e = 0; e < NE; ++e) {
      p[e] *= inv;
      atomicAdd(&blkp[e], p[e]);
      if (p[e] > v1) { v2 = v1; i2 = i1; v1 = p[e]; i1 = e; }
      else if (p[e] > v2) { v2 = p[e]; i2 = e; }
    }
    float wsum = v1 + v2;
    int l1 = atomicAdd(&cnt[i1], 1);
    int l2 = atomicAdd(&cnt[i2], 1);
    slotE[token * 2] = i1;     slotLoc[token * 2] = l1;     slotW[token * 2] = v1 / wsum;
    slotE[token * 2 + 1] = i2; slotLoc[token * 2 + 1] = l2; slotW[token * 2 + 1] = v2 / wsum;
  }
  __syncthreads();
  if (t < NE) atomicAdd(&psumG[t], blkp[t]);
}

// ---------------- finalize: offsets + aux loss (trivial) ----------------
__global__ void k_finalize(const float* __restrict__ psumG, const int* __restrict__ cnt,
                           int* __restrict__ off, float* __restrict__ out_aux) {
  if (threadIdx.x == 0) {
    int o = 0;
    float a = 0.f;
    for (int e = 0; e < NE; ++e) {
      off[e] = o;
      o += cnt[e];
      a += ((float)cnt[e] / (float)NSLOT) * (psumG[e] / (float)NT);
    }
    off[NE] = o;
    out_aux[0] = (float)NE * a * 0.01f;
  }
}

// ---------------- scatter: build per-expert row lists ----------------
__global__ void k_scatter(const int* __restrict__ slotE, const int* __restrict__ slotLoc,
                          const float* __restrict__ slotW, const int* __restrict__ off,
                          int* __restrict__ rowTok, float* __restrict__ rowW) {
  int i = blockIdx.x * 256 + threadIdx.x;  // < NSLOT
  int pos = off[slotE[i]] + slotLoc[i];
  if (pos < 0) pos = 0;
  if (pos >= NSLOT) pos = NSLOT - 1;
  rowTok[pos] = i >> 1;
  rowW[pos] = slotW[i];
}

// Stage one 128x32 A-tile + B-tile (16 KB) into buffer `bf`: 4 gload16/thread.
#define STG(bf) do { \
    gload16(srcA0, &As[bf][c0 * 8]); \
    gload16(srcA1, &As[bf][c1 * 8]); \
    gload16(srcB0, &Bs[bf][c0 * 8]); \
    gload16(srcB1, &Bs[bf][c1 * 8]); \
    srcA0 += 32; srcA1 += 32; srcB0 += 32; srcB1 += 32; \
  } while (0)

// ---------------- GEMM1: h = gelu(xb[gather] @ W1[e] + b1[e]) ----------------
// R9-exact: 128x128 tile, BK=32, 4 waves, 3-buffer depth-2, 1 barrier/step,
// n-inner ordering (R9-measured fastest: 161 us).
__global__ __launch_bounds__(256, 3) void k_gemm1(
    const u16* __restrict__ xb, const u16* __restrict__ w1t,
    const float* __restrict__ b1, u16* __restrict__ hbuf,
    const int* __restrict__ cnt, const int* __restrict__ off,
    const int* __restrict__ rowTok) {
  const int NWG = NE * 32 * 32;
  int bid = blockIdx.x;
  int wg = (bid & 7) * (NWG / 8) + (bid >> 3);
  int e = wg >> 10;
  int rem = wg & 1023;
  int m0 = (rem >> 5) * 128;
  int n0 = (rem & 31) * 128;
  int ce = cnt[e];
  if (m0 >= ce) return;
  int oe = off[e];
  __shared__ u16 As[3][128 * 32];
  __shared__ u16 Bs[3][128 * 32];
  __shared__ int rtok[128];
  int t = threadIdx.x;
  if (t < 128) {
    int r = m0 + t;
    if (r >= ce) r = ce - 1;
    int tok = rowTok[oe + r];
    rtok[t] = (tok < 0) ? 0 : (tok >= NT ? NT - 1 : tok);
  }
  __syncthreads();
  // chunk swizzle: LDS chunk c holds global 16B-chunk j = (c&3) ^ ((c>>3)&3)
  int c0 = t, c1 = t + 256;
  int js0 = (c0 & 3) ^ ((c0 >> 3) & 3);
  int js1 = (c1 & 3) ^ ((c1 >> 3) & 3);
  const u16* srcA0 = xb + (size_t)rtok[c0 >> 2] * HD + js0 * 8;
  const u16* srcA1 = xb + (size_t)rtok[c1 >> 2] * HD + js1 * 8;
  const u16* bb = w1t + (size_t)e * ID * HD + (size_t)n0 * HD;
  const u16* srcB0 = bb + (size_t)(c0 >> 2) * HD + js0 * 8;
  const u16* srcB1 = bb + (size_t)(c1 >> 2) * HD + js1 * 8;
  int wave = t >> 6, lane = t & 63;
  int wr = wave >> 1, wc = wave & 1;
  int arow = wr * 64 + (lane & 15);
  int aoff = arow * 32 + ((lane >> 4) ^ ((arow >> 1) & 3)) * 8;   // swizzled read
  int brow = wc * 64 + (lane & 15);
  int boff = brow * 32 + ((lane >> 4) ^ ((brow >> 1) & 3)) * 8;
  f32x4 acc[4][4] = {};
  const int NK = HD / 32;             // 32
  STG(0);
  STG(1);
  int rb = 0;
  for (int kt = 0; kt < NK; ++kt) {
    if (kt + 1 < NK) asm volatile("s_waitcnt vmcnt(4)" ::: "memory");
    else             asm volatile("s_waitcnt vmcnt(0)" ::: "memory");
    __builtin_amdgcn_s_barrier();
    const u16* ap = &As[rb][aoff];
    const u16* bp = &Bs[rb][boff];
    bf16x8 af[4], bfr[4];
#pragma unroll
    for (int m = 0; m < 4; ++m) af[m] = *(const bf16x8*)(ap + m * 16 * 32);
#pragma unroll
    for (int n = 0; n < 4; ++n) bfr[n] = *(const bf16x8*)(bp + n * 16 * 32);
#pragma unroll
    for (int m = 0; m < 4; ++m)
#pragma unroll
      for (int n = 0; n < 4; ++n)
        acc[m][n] = __builtin_amdgcn_mfma_f32_16x16x32_bf16(af[m], bfr[n], acc[m][n], 0, 0, 0);
    if (kt + 2 < NK) {                // restage buf last read at step kt-1
      int sb = rb + 2; if (sb >= 3) sb -= 3;
      STG(sb);
    }
    rb = (rb == 2) ? 0 : rb + 1;
  }
  const float* b1e = b1 + (size_t)e * ID + n0;
#pragma unroll
  for (int n = 0; n < 4; ++n) {
    int col = wc * 64 + n * 16 + (lane & 15);
    float bias = b1e[col];
#pragma unroll
    for (int m = 0; m < 4; ++m) {
      int rbase = wr * 64 + m * 16 + (lane >> 4) * 4;
#pragma unroll
      for (int r = 0; r < 4; ++r) {
        int grow = m0 + rbase + r;
        if (grow < ce) {
          float v = acc[m][n][r] + bias;
          hbuf[(size_t)(oe + grow) * ID + n0 + col] = f2b(gelu_tanh(v));
        }
      }
    }
  }
}

// ------- GEMM2 (split-K=2, fused combine): out[tok] += (h@W2 + b2) * w -------
// R9-exact: n-inner ordering (162 us measured).
__global__ __launch_bounds__(256, 3) void k_gemm2(
    const u16* __restrict__ hbuf, const u16* __restrict__ w2t,
    const float* __restrict__ b2, float* __restrict__ out,
    const int* __restrict__ cnt, const int* __restrict__ off,
    const int* __restrict__ rowTok, const float* __restrict__ rowW) {
  const int NWG = NE * 32 * 2 * 8;
  int bid = blockIdx.x;
  int wg = (bid & 7) * (NWG / 8) + (bid >> 3);
  int e = wg >> 9;
  int rem = wg & 511;
  int m0 = (rem >> 4) * 128;
  int ks = (rem >> 3) & 1;
  int n0 = (rem & 7) * 128;
  int ce = cnt[e];
  if (m0 >= ce) return;
  int oe = off[e];
  int k0 = ks * (ID / 2);
  __shared__ u16 As[3][128 * 32];
  __shared__ u16 Bs[3][128 * 32];
  __shared__ int rtok[128];
  __shared__ float rw[128];
  int t = threadIdx.x;
  if (t < 128) {
    int r = m0 + t;
    int rc = (r < ce) ? r : ce - 1;
    int tok = rowTok[oe + rc];
    rtok[t] = (tok < 0) ? 0 : (tok >= NT ? NT - 1 : tok);
    rw[t] = (r < ce) ? rowW[oe + r] : 0.0f;
  }
  __syncthreads();
  int c0 = t, c1 = t + 256;
  int js0 = (c0 & 3) ^ ((c0 >> 3) & 3);
  int js1 = (c1 & 3) ^ ((c1 >> 3) & 3);
  int rA0 = m0 + (c0 >> 2); if (rA0 >= ce) rA0 = ce - 1;
  int rA1 = m0 + (c1 >> 2); if (rA1 >= ce) rA1 = ce - 1;
  const u16* srcA0 = hbuf + (size_t)(oe + rA0) * ID + k0 + js0 * 8;
  const u16* srcA1 = hbuf + (size_t)(oe + rA1) * ID + k0 + js1 * 8;
  const u16* bb = w2t + (size_t)e * HD * ID + (size_t)n0 * ID + k0;
  const u16* srcB0 = bb + (size_t)(c0 >> 2) * ID + js0 * 8;
  const u16* srcB1 = bb + (size_t)(c1 >> 2) * ID + js1 * 8;
  int wave = t >> 6, lane = t & 63;
  int wr = wave >> 1, wc = wave & 1;
  int arow = wr * 64 + (lane & 15);
  int aoff = arow * 32 + ((lane >> 4) ^ ((arow >> 1) & 3)) * 8;
  int brow = wc * 64 + (lane & 15);
  int boff = brow * 32 + ((lane >> 4) ^ ((brow >> 1) & 3)) * 8;
  f32x4 acc[4][4] = {};
  const int NK = (ID / 2) / 32;       // 64
  STG(0);
  STG(1);
  int rb = 0;
  for (int kt = 0; kt < NK; ++kt) {
    if (kt + 1 < NK) asm volatile("s_waitcnt vmcnt(4)" ::: "memory");
    else             asm volatile("s_waitcnt vmcnt(0)" ::: "memory");
    __builtin_amdgcn_s_barrier();
    const u16* ap = &As[rb][aoff];
    const u16* bp = &Bs[rb][boff];
    bf16x8 af[4], bfr[4];
#pragma unroll
    for (int m = 0; m < 4; ++m) af[m] = *(const bf16x8*)(ap + m * 16 * 32);
#pragma unroll
    for (int n = 0; n < 4; ++n) bfr[n] = *(const bf16x8*)(bp + n * 16 * 32);
#pragma unroll
    for (int m = 0; m < 4; ++m)
#pragma unroll
      for (int n = 0; n < 4; ++n)
        acc[m][n] = __builtin_amdgcn_mfma_f32_16x16x32_bf16(af[m], bfr[n], acc[m][n], 0, 0, 0);
    if (kt + 2 < NK) {
      int sb = rb + 2; if (sb >= 3) sb -= 3;
      STG(sb);
    }
    rb = (rb == 2) ? 0 : rb + 1;
  }
  const float* b2e = b2 + (size_t)e * HD + n0;
#pragma unroll
  for (int n = 0; n < 4; ++n) {
    int col = wc * 64 + n * 16 + (lane & 15);
    float bias = (ks == 0) ? b2e[col] : 0.0f;
#pragma unroll
    for (int m = 0; m < 4; ++m) {
      int rbase = wr * 64 + m * 16 + (lane >> 4) * 4;
#pragma unroll
      for (int r = 0; r < 4; ++r) {
        int grow = m0 + rbase + r;
        if (grow < ce) {
          float v = (acc[m][n][r] + bias) * rw[rbase + r];
          atomicAdd(&out[(size_t)rtok[rbase + r] * HD + n0 + col], v);
        }
      }
    }
  }
}

extern "C" void kernel_launch(void* const* d_in, const int* in_sizes, int n_in,
                              void* d_out, int out_size, void* d_ws, size_t ws_size,
                              hipStream_t stream) {
  const float* x  = (const float*)d_in[0];
  const float* Wr = (const float*)d_in[1];
  const float* br = (const float*)d_in[2];
  const float* W1 = (const float*)d_in[3];
  const float* b1 = (const float*)d_in[4];
  const float* W2 = (const float*)d_in[5];
  const float* b2 = (const float*)d_in[6];
  float* out = (float*)d_out;

  char* ws = (char*)d_ws;
  size_t o = 0;
  auto alloc = [&](size_t bytes) {
    void* p = ws + o;
    o = (o + bytes + 255) & ~(size_t)255;
    return p;
  };
  u16* xb    = (u16*)alloc((size_t)NT * HD * 2);
  u16* w1t   = (u16*)alloc((size_t)NE * ID * HD * 2);
  u16* w2t   = (u16*)alloc((size_t)NE * ID * HD * 2);
  u16* hbuf  = (u16*)alloc((size_t)NSLOT * ID * 2);
  int* cnt     = (int*)alloc(NE * 4);
  float* psumG = (float*)alloc(NE * 4);
  int* off     = (int*)alloc(16 * 4);
  int* slotE   = (int*)alloc(NSLOT * 4);
  int* slotLoc = (int*)alloc(NSLOT * 4);
  float* slotW = (float*)alloc(NSLOT * 4);
  int* rowTok  = (int*)alloc(NSLOT * 4);
  float* rowW  = (float*)alloc(NSLOT * 4);

  if (ws_size < o) return;  // workspace too small: fail cleanly, not a fault

  (void)hipMemsetAsync(cnt, 0, NE * 4, stream);
  (void)hipMemsetAsync(psumG, 0, NE * 4, stream);
  (void)hipMemsetAsync(out, 0, (size_t)out_size * 4, stream);
  k_transpose2<<<16384, 256, 0, stream>>>(W1, w1t, W2, w2t);
  k_router<<<NT / 4, 256, 0, stream>>>(x, Wr, br, cnt, slotE, slotLoc, slotW, psumG, xb);
  k_finalize<<<1, 64, 0, stream>>>(psumG, cnt, off, out + (size_t)NT * HD);
  k_scatter<<<NSLOT / 256, 256, 0, stream>>>(slotE, slotLoc, slotW, off, rowTok, rowW);
  k_gemm1<<<NE * 32 * 32, 256, 0, stream>>>(xb, w1t, b1, hbuf, cnt, off, rowTok);
  k_gemm2<<<NE * 32 * 2 * 8, 256, 0, stream>>>(hbuf, w2t, b2, out, cnt, off, rowTok, rowW);
}